// Round 4
// baseline (322.599 us; speedup 1.0000x reference)
//
#include <hip/hip_runtime.h>

typedef unsigned short u16;
typedef __bf16 bf16x8_t __attribute__((ext_vector_type(8)));
typedef float  f32x4_t  __attribute__((ext_vector_type(4)));
typedef u16    us8_t    __attribute__((ext_vector_type(8)));
typedef u16    us4_t    __attribute__((ext_vector_type(4)));

__device__ __forceinline__ u16 f2bf(float f) {
    __bf16 h = (__bf16)f;
    return __builtin_bit_cast(u16, h);
}
__device__ __forceinline__ bf16x8_t ld_bf8(const u16* p) {
    us8_t u = *(const us8_t*)p;
    return __builtin_bit_cast(bf16x8_t, u);
}
__device__ __forceinline__ f32x4_t mfma16(bf16x8_t a, bf16x8_t b, f32x4_t c) {
    return __builtin_amdgcn_mfma_f32_16x16x32_bf16(a, b, c, 0, 0, 0);
}

// async global->LDS, 16B per lane. LDS dest MUST be base + lane*16 (wave-uniform base).
__device__ __forceinline__ void dma16(const u16* g, u16* l) {
#if __has_builtin(__builtin_amdgcn_global_load_lds)
    __builtin_amdgcn_global_load_lds((const __attribute__((address_space(1))) unsigned int*)(g),
                                     (__attribute__((address_space(3))) unsigned int*)(l), 16, 0, 0);
#else
    *(us8_t*)l = *(const us8_t*)g;
#endif
}

// ---------------- fp32 -> bf16 convert (q,k,v inputs) ----------------
__global__ __launch_bounds__(256) void cvt_kernel(
    const float* __restrict__ q, const float* __restrict__ k, const float* __restrict__ v,
    u16* __restrict__ Qc, u16* __restrict__ Kc, u16* __restrict__ Vc)
{
    const int z = blockIdx.y;
    const float* src = (z == 0) ? q : (z == 1) ? k : v;
    u16* dst = (z == 0) ? Qc : (z == 1) ? Kc : Vc;
    const size_t i = ((size_t)blockIdx.x * 256 + threadIdx.x) * 8;
    float4 a = *(const float4*)(src + i);
    float4 b = *(const float4*)(src + i + 4);
    us8_t w;
    w[0] = f2bf(a.x); w[1] = f2bf(a.y); w[2] = f2bf(a.z); w[3] = f2bf(a.w);
    w[4] = f2bf(b.x); w[5] = f2bf(b.y); w[6] = f2bf(b.z); w[7] = f2bf(b.w);
    *(us8_t*)(dst + i) = w;
}

// ---------------- weight transpose+convert: fp32 [k][n] -> bf16 [n][k] ----------------
__global__ __launch_bounds__(256) void transpose_w_kernel(
    const float* __restrict__ w0, const float* __restrict__ w1,
    const float* __restrict__ w2, const float* __restrict__ w3,
    u16* __restrict__ out)
{
    __shared__ u16 t[64][65];
    const int z = blockIdx.z;
    const float* src = (z == 0) ? w0 : (z == 1) ? w1 : (z == 2) ? w2 : w3;
    u16* dst = out + (size_t)z * 1024 * 1024;
    const int bk = blockIdx.x * 64, bn = blockIdx.y * 64;
    const int tid = threadIdx.x;
    const int r = tid >> 2, c4 = tid & 3;
    for (int i = 0; i < 4; i++) {
        float4 v = *(const float4*)(src + (size_t)(bk + r) * 1024 + bn + c4 * 16 + i * 4);
        t[r][c4 * 16 + i * 4 + 0] = f2bf(v.x);
        t[r][c4 * 16 + i * 4 + 1] = f2bf(v.y);
        t[r][c4 * 16 + i * 4 + 2] = f2bf(v.z);
        t[r][c4 * 16 + i * 4 + 3] = f2bf(v.w);
    }
    __syncthreads();
    for (int i = 0; i < 2; i++) {
        us8_t w;
        for (int j = 0; j < 8; j++) w[j] = t[c4 * 16 + i * 8 + j][r];
        *(us8_t*)(dst + (size_t)(bn + r) * 1024 + bk + c4 * 16 + i * 8) = w;
    }
}

// ---------------- mask pack: int32 [B,1,S,S] -> 1 bit per key ----------------
__global__ __launch_bounds__(256) void pack_mask_kernel(
    const int* __restrict__ mask, unsigned* __restrict__ mp)
{
    const int w = blockIdx.x * 256 + threadIdx.x;
    const int* src = mask + (size_t)w * 32;
    unsigned bits = 0u;
    for (int i = 0; i < 32; i += 4) {
        int4 v = *(const int4*)(src + i);
        bits |= (unsigned)(v.x != 0) << (i + 0);
        bits |= (unsigned)(v.y != 0) << (i + 1);
        bits |= (unsigned)(v.z != 0) << (i + 2);
        bits |= (unsigned)(v.w != 0) << (i + 3);
    }
    mp[w] = bits;
}

// ---------------- fused QKV projection GEMM (m97-style, DMA staging) ----------------
// z=0: Q -> head-major K-swizzled; z=1: K same; z=2: V -> tiled pi-permuted+swizzled Vtt.
// Q/K swizzle: within a 64-u16 row s, 16B chunk j stored at j ^ (s&7).
// Vtt layout: tile (b,h,kt): d*128 + ((sl&15)^(d&7))*8 + (sl>>4)  [pi: pos=(sl&15)*8+(sl>>4)]
__global__ __launch_bounds__(256) void qkv_gemm_kernel(
    const u16* __restrict__ Qc, const u16* __restrict__ Kc, const u16* __restrict__ Vc,
    const u16* __restrict__ Wt,
    const float* __restrict__ bq, const float* __restrict__ bk, const float* __restrict__ bv,
    u16* __restrict__ Qh, u16* __restrict__ Kh, u16* __restrict__ Vtt)
{
    __shared__ __align__(16) u16 As[4096];
    __shared__ __align__(16) u16 Bs[4096];
    const int z = blockIdx.z;
    const u16* A = (z == 0) ? Qc : (z == 1) ? Kc : Vc;
    const u16* W = Wt + (size_t)z * 1048576;
    const float* bias = (z == 0) ? bq : (z == 1) ? bk : bv;

    const int m0 = blockIdx.x * 128, n0 = blockIdx.y * 128;
    const int tid = threadIdx.x, lane = tid & 63, wave = tid >> 6;
    const int l15 = lane & 15, quad = lane >> 4;
    const int wm = (wave & 1) * 64, wn = (wave >> 1) * 64;
    const int srow = lane >> 2, scol = (lane & 3) * 8;

    const f32x4_t z4 = {0.f, 0.f, 0.f, 0.f};
    f32x4_t acc[4][4];
    for (int i = 0; i < 4; i++) for (int j = 0; j < 4; j++) acc[i][j] = z4;

    for (int k0 = 0; k0 < 1024; k0 += 32) {
        #pragma unroll
        for (int i = 0; i < 2; i++) {
            dma16(A + (size_t)(m0 + wave * 32 + i * 16 + srow) * 1024 + k0 + scol,
                  &As[wave * 1024 + i * 512 + lane * 8]);
            dma16(W + (size_t)(n0 + wave * 32 + i * 16 + srow) * 1024 + k0 + scol,
                  &Bs[wave * 1024 + i * 512 + lane * 8]);
        }
        __syncthreads();
        bf16x8_t af[4], bfr[4];
        #pragma unroll
        for (int i = 0; i < 4; i++) af[i] = ld_bf8(&As[(wm + i * 16 + l15) * 32 + quad * 8]);
        #pragma unroll
        for (int j = 0; j < 4; j++) bfr[j] = ld_bf8(&Bs[(wn + j * 16 + l15) * 32 + quad * 8]);
        #pragma unroll
        for (int i = 0; i < 4; i++)
            #pragma unroll
            for (int j = 0; j < 4; j++)
                acc[i][j] = mfma16(af[i], bfr[j], acc[i][j]);
        __syncthreads();
    }

    #pragma unroll
    for (int i = 0; i < 4; i++) {
        const int m = m0 + wm + i * 16 + quad * 4;
        #pragma unroll
        for (int j = 0; j < 4; j++) {
            const int gn = n0 + wn + j * 16 + l15;
            const float bb = bias[gn];
            const int h = gn >> 6, dh = gn & 63;
            if (z < 2) {
                u16* Y = z ? Kh : Qh;
                const int jc = dh >> 3, e = dh & 7;
                #pragma unroll
                for (int r = 0; r < 4; r++) {
                    const int mm = m + r;
                    const int b = mm >> 11, s = mm & 2047;
                    Y[((size_t)(b * 16 + h) * 2048 + s) * 64 + ((jc ^ (s & 7)) * 8) + e] =
                        f2bf(acc[i][j][r] + bb);
                }
            } else {
                const int b = m >> 11, sh = m & 2047, kt2 = sh >> 7, sl = sh & 127;
                size_t tbase = (((size_t)(b * 16 + h) * 16 + kt2) * 8192)
                             + (size_t)dh * 128 + (sl >> 4);
                #pragma unroll
                for (int r = 0; r < 4; r++)
                    Vtt[tbase + (size_t)((((sl + r) & 15) ^ (dh & 7)) * 8)] =
                        f2bf(acc[i][j][r] + bb);
            }
        }
    }
}

// ---------------- output projection GEMM (m97-style): out = CT @ Wo^T + bo (fp32) ----------
__global__ __launch_bounds__(256) void out_gemm_kernel(
    const u16* __restrict__ X, const u16* __restrict__ Wt,
    const float* __restrict__ bias, float* __restrict__ Y)
{
    __shared__ __align__(16) u16 As[4096];
    __shared__ __align__(16) u16 Bs[4096];
    const int m0 = blockIdx.x * 128, n0 = blockIdx.y * 128;
    const int tid = threadIdx.x, lane = tid & 63, wave = tid >> 6;
    const int l15 = lane & 15, quad = lane >> 4;
    const int wm = (wave & 1) * 64, wn = (wave >> 1) * 64;
    const int srow = lane >> 2, scol = (lane & 3) * 8;

    const f32x4_t z4 = {0.f, 0.f, 0.f, 0.f};
    f32x4_t acc[4][4];
    for (int i = 0; i < 4; i++) for (int j = 0; j < 4; j++) acc[i][j] = z4;

    for (int k0 = 0; k0 < 1024; k0 += 32) {
        #pragma unroll
        for (int i = 0; i < 2; i++) {
            dma16(X + (size_t)(m0 + wave * 32 + i * 16 + srow) * 1024 + k0 + scol,
                  &As[wave * 1024 + i * 512 + lane * 8]);
            dma16(Wt + (size_t)(n0 + wave * 32 + i * 16 + srow) * 1024 + k0 + scol,
                  &Bs[wave * 1024 + i * 512 + lane * 8]);
        }
        __syncthreads();
        bf16x8_t af[4], bfr[4];
        #pragma unroll
        for (int i = 0; i < 4; i++) af[i] = ld_bf8(&As[(wm + i * 16 + l15) * 32 + quad * 8]);
        #pragma unroll
        for (int j = 0; j < 4; j++) bfr[j] = ld_bf8(&Bs[(wn + j * 16 + l15) * 32 + quad * 8]);
        #pragma unroll
        for (int i = 0; i < 4; i++)
            #pragma unroll
            for (int j = 0; j < 4; j++)
                acc[i][j] = mfma16(af[i], bfr[j], acc[i][j]);
        __syncthreads();
    }

    #pragma unroll
    for (int i = 0; i < 4; i++) {
        const int m = m0 + wm + i * 16 + quad * 4;
        #pragma unroll
        for (int j = 0; j < 4; j++) {
            const int gn = n0 + wn + j * 16 + l15;
            const float bb = bias[gn];
            #pragma unroll
            for (int r = 0; r < 4; r++)
                Y[(size_t)(m + r) * 1024 + gn] = acc[i][j][r] + bb;
        }
    }
}

// ---------------- flash attention v4 ----------------
// grid (qb=16, h=16, b=2) = 512 blocks (2/CU exact). 256 thr = 4 waves x 32 q-rows.
// Fixed-max softmax (M=12, shift-invariant), deferred l-sum, pi-permuted keys so
// P writes are 1 ds_write_b128 per row. K16+V16+P32 = 64KB LDS. Phase-shifted
// K/V DMA prefetch: K(t+1) after QK barrier, V(t+1) after PV barrier.
__global__ __launch_bounds__(256) void attn_kernel(
    const u16* __restrict__ Qh, const u16* __restrict__ Kh,
    const u16* __restrict__ Vtt, const unsigned* __restrict__ mp,
    u16* __restrict__ C)
{
    __shared__ __align__(16) u16 Ks[8192];
    __shared__ __align__(16) u16 Vs[8192];
    __shared__ __align__(16) u16 Ps[16384];
    const int qb = blockIdx.x, h = blockIdx.y, b = blockIdx.z;
    const int tid = threadIdx.x, lane = tid & 63, wave = tid >> 6;
    const int l15 = lane & 15, quad = lane >> 4;
    const int q0 = qb * 128 + wave * 32;
    const int grow = b * 2048 + q0;
    const size_t headoff = (size_t)(b * 16 + h) * 131072;
    const u16* Qg = Qh + headoff;
    const u16* Kg = Kh + headoff;
    const u16* Vg = Vtt + headoff;

    bf16x8_t aq[2][2];
    #pragma unroll
    for (int h2 = 0; h2 < 2; h2++)
        #pragma unroll
        for (int ks = 0; ks < 2; ks++)
            aq[h2][ks] = ld_bf8(Qg + (size_t)(q0 + h2 * 16 + l15) * 64
                                   + (((ks * 4 + quad) ^ (l15 & 7)) * 8));

    const f32x4_t z4 = {0.f, 0.f, 0.f, 0.f};
    f32x4_t o[2][4];
    float psum[2][4];
    #pragma unroll
    for (int h2 = 0; h2 < 2; h2++)
        #pragma unroll
        for (int i = 0; i < 4; i++) { o[h2][i] = z4; psum[h2][i & 3] = 0.f; }
    #pragma unroll
    for (int h2 = 0; h2 < 2; h2++)
        #pragma unroll
        for (int r = 0; r < 4; r++) psum[h2][r] = 0.f;

    u16* Pw = &Ps[wave * 4096];
    const unsigned* mb0 = mp + (size_t)(b * 2048 + q0 + quad * 4) * 64;

    // DMA roles: waves 0-1 stage K halves, waves 2-3 stage V halves
    const u16* gsrc = ((wave >= 2) ? Vg : Kg) + (wave & 1) * 4096;
    u16* ldst = ((wave >= 2) ? Vs : Ks) + (wave & 1) * 4096;

    // preload tile 0
    #pragma unroll
    for (int i = 0; i < 8; i++)
        dma16(gsrc + i * 512 + lane * 8, ldst + i * 512 + lane * 8);
    __syncthreads();

    for (int kt = 0; kt < 16; ++kt) {
        // mask words for this tile (needed after QK; latency hides under MFMAs)
        int4 mw[2][4];
        #pragma unroll
        for (int h2 = 0; h2 < 2; h2++)
            #pragma unroll
            for (int r = 0; r < 4; r++)
                mw[h2][r] = *(const int4*)(mb0 + h2 * 1024 + r * 64 + kt * 4);

        // --- QK^T: K frags read once, used by both row-halves ---
        f32x4_t sc[2][8];
        #pragma unroll
        for (int st = 0; st < 8; st++) {
            const u16* kp = &Ks[(st * 16 + l15) * 64];
            bf16x8_t b0 = ld_bf8(kp + ((quad ^ (l15 & 7)) * 8));
            bf16x8_t b1 = ld_bf8(kp + (((4 + quad) ^ (l15 & 7)) * 8));
            sc[0][st] = mfma16(aq[0][1], b1, mfma16(aq[0][0], b0, z4));
            sc[1][st] = mfma16(aq[1][1], b1, mfma16(aq[1][0], b0, z4));
        }
        __syncthreads();   // K(t) consumed by all waves

        if (kt < 15 && wave < 2) {
            const u16* g = gsrc + (kt + 1) * 8192;
            #pragma unroll
            for (int i = 0; i < 8; i++)
                dma16(g + i * 512 + lane * 8, ldst + i * 512 + lane * 8);
        }

        // --- fixed-max softmax + packed P write (1 b128 per row) ---
        #pragma unroll
        for (int h2 = 0; h2 < 2; h2++) {
            #pragma unroll
            for (int r = 0; r < 4; r++) {
                const unsigned* mwp = (const unsigned*)&mw[h2][r];
                const unsigned a0 = mwp[0] >> l15, a1 = mwp[1] >> l15;
                const unsigned a2 = mwp[2] >> l15, a3 = mwp[3] >> l15;
                us8_t pk;
                float ps = 0.f;
                #pragma unroll
                for (int st = 0; st < 8; st++) {
                    const unsigned aw = (st < 2) ? a0 : (st < 4) ? a1 : (st < 6) ? a2 : a3;
                    const bool msk = (aw >> ((st & 1) << 4)) & 1u;
                    const float t = fmaf(sc[h2][st][r], 0.125f, msk ? -1e5f : -12.0f);
                    const float p = __expf(t);
                    ps += p;
                    pk[st] = f2bf(p);
                }
                psum[h2][r] += ps;
                *(us8_t*)&Pw[(h2 * 16 + quad * 4 + r) * 128 + l15 * 8] = pk;
            }
        }

        // order P writes before P reads (wave-private)
        __builtin_amdgcn_wave_barrier();
        __builtin_amdgcn_s_waitcnt(0xC07F);   // lgkmcnt(0)
        __builtin_amdgcn_wave_barrier();

        // --- PV: V frags read once, used by both row-halves ---
        #pragma unroll
        for (int c = 0; c < 4; c++) {
            bf16x8_t ap0 = ld_bf8(&Pw[l15 * 128 + c * 32 + quad * 8]);
            bf16x8_t ap1 = ld_bf8(&Pw[(16 + l15) * 128 + c * 32 + quad * 8]);
            #pragma unroll
            for (int nt = 0; nt < 4; nt++) {
                bf16x8_t bv = ld_bf8(&Vs[(nt * 16 + l15) * 128
                                         + (((c * 4 + quad) ^ (l15 & 7)) * 8)]);
                o[0][nt] = mfma16(ap0, bv, o[0][nt]);
                o[1][nt] = mfma16(ap1, bv, o[1][nt]);
            }
        }
        __syncthreads();   // V(t)+P consumed; drains K(t+1) DMA (issued ~2000 cyc ago)

        if (kt < 15 && wave >= 2) {
            const u16* g = gsrc + (kt + 1) * 8192;
            #pragma unroll
            for (int i = 0; i < 8; i++)
                dma16(g + i * 512 + lane * 8, ldst + i * 512 + lane * 8);
        }
    }

    // deferred l-reduction + store
    #pragma unroll
    for (int h2 = 0; h2 < 2; h2++) {
        #pragma unroll
        for (int r = 0; r < 4; r++) {
            float s = psum[h2][r];
            #pragma unroll
            for (int off = 1; off < 16; off <<= 1) s += __shfl_xor(s, off);
            const float invl = 1.0f / s;
            const int row = grow + h2 * 16 + quad * 4 + r;
            #pragma unroll
            for (int nt = 0; nt < 4; nt++)
                C[(size_t)row * 1024 + h * 64 + nt * 16 + l15] = f2bf(o[h2][nt][r] * invl);
        }
    }
}

extern "C" void kernel_launch(void* const* d_in, const int* in_sizes, int n_in,
                              void* d_out, int out_size, void* d_ws, size_t ws_size,
                              hipStream_t stream) {
    const float* q    = (const float*)d_in[0];
    const float* k    = (const float*)d_in[1];
    const float* v    = (const float*)d_in[2];
    const int*   mask = (const int*)d_in[3];
    const float* wq   = (const float*)d_in[4];
    const float* bq   = (const float*)d_in[5];
    const float* wk   = (const float*)d_in[6];
    const float* bk   = (const float*)d_in[7];
    const float* wv   = (const float*)d_in[8];
    const float* bv   = (const float*)d_in[9];
    const float* wo   = (const float*)d_in[10];
    const float* bo   = (const float*)d_in[11];
    float* out = (float*)d_out;

    char* ws = (char*)d_ws;
    const size_t MB = 1ull << 20;
    u16* Wt      = (u16*)(ws);              // 8 MB: 4 weights bf16 [n][k]
    u16* Qc      = (u16*)(ws + 8 * MB);     // 8 MB bf16 input q
    u16* Kc      = (u16*)(ws + 16 * MB);    // 8 MB bf16 input k
    u16* Vc      = (u16*)(ws + 24 * MB);    // 8 MB bf16 input v
    u16* Qh      = (u16*)(ws + 32 * MB);    // 8 MB head-major swizzled
    u16* Kh      = (u16*)(ws + 40 * MB);    // 8 MB head-major swizzled
    u16* Vtt     = (u16*)(ws + 48 * MB);    // 8 MB tiled pi-permuted swizzled
    u16* CT      = (u16*)(ws + 8 * MB);     // reuse Qc (dead after qkv_gemm)
    unsigned* mp = (unsigned*)(ws + 56 * MB); // 1 MB

    cvt_kernel<<<dim3(2048, 3), 256, 0, stream>>>(q, k, v, Qc, Kc, Vc);
    transpose_w_kernel<<<dim3(16, 16, 4), 256, 0, stream>>>(wq, wk, wv, wo, Wt);
    pack_mask_kernel<<<dim3(1024), 256, 0, stream>>>(mask, mp);

    qkv_gemm_kernel<<<dim3(32, 8, 3), 256, 0, stream>>>(
        Qc, Kc, Vc, Wt, bq, bk, bv, Qh, Kh, Vtt);

    attn_kernel<<<dim3(16, 16, 2), 256, 0, stream>>>(Qh, Kh, Vtt, mp, CT);

    out_gemm_kernel<<<dim3(32, 8), 256, 0, stream>>>(CT, Wt + 3ull * 1048576, bo, out);
}

// Round 5
// 293.592 us; speedup vs baseline: 1.0988x; 1.0988x over previous
//
#include <hip/hip_runtime.h>

typedef unsigned short u16;
typedef __bf16 bf16x8_t __attribute__((ext_vector_type(8)));
typedef float  f32x4_t  __attribute__((ext_vector_type(4)));
typedef u16    us8_t    __attribute__((ext_vector_type(8)));
typedef u16    us4_t    __attribute__((ext_vector_type(4)));

__device__ __forceinline__ u16 f2bf(float f) {
    __bf16 h = (__bf16)f;
    return __builtin_bit_cast(u16, h);
}
__device__ __forceinline__ bf16x8_t ld_bf8(const u16* p) {
    us8_t u = *(const us8_t*)p;
    return __builtin_bit_cast(bf16x8_t, u);
}
__device__ __forceinline__ f32x4_t mfma16(bf16x8_t a, bf16x8_t b, f32x4_t c) {
    return __builtin_amdgcn_mfma_f32_16x16x32_bf16(a, b, c, 0, 0, 0);
}

// async global->LDS, 16B per lane. LDS dest MUST be base + lane*16 (wave-uniform base).
__device__ __forceinline__ void dma16(const u16* g, u16* l) {
#if __has_builtin(__builtin_amdgcn_global_load_lds)
    __builtin_amdgcn_global_load_lds((const __attribute__((address_space(1))) unsigned int*)(g),
                                     (__attribute__((address_space(3))) unsigned int*)(l), 16, 0, 0);
#else
    *(us8_t*)l = *(const us8_t*)g;
#endif
}

// ---------------- fused prep: cvt (6144 blk) + weight transpose (1024) + mask pack (1024) ----
__global__ __launch_bounds__(256) void prep_kernel(
    const float* __restrict__ q, const float* __restrict__ k, const float* __restrict__ v,
    const int* __restrict__ mask,
    const float* __restrict__ w0, const float* __restrict__ w1,
    const float* __restrict__ w2, const float* __restrict__ w3,
    u16* __restrict__ Qc, u16* __restrict__ Kc, u16* __restrict__ Vc,
    u16* __restrict__ Wt, unsigned* __restrict__ mp)
{
    __shared__ u16 t[64][65];
    const int bid = blockIdx.x, tid = threadIdx.x;
    if (bid < 6144) {
        // fp32 -> bf16 convert of q,k,v
        const int z = bid >> 11, x = bid & 2047;
        const float* src = (z == 0) ? q : (z == 1) ? k : v;
        u16* dst = (z == 0) ? Qc : (z == 1) ? Kc : Vc;
        const size_t i = ((size_t)x * 256 + tid) * 8;
        float4 a = *(const float4*)(src + i);
        float4 b = *(const float4*)(src + i + 4);
        us8_t w;
        w[0] = f2bf(a.x); w[1] = f2bf(a.y); w[2] = f2bf(a.z); w[3] = f2bf(a.w);
        w[4] = f2bf(b.x); w[5] = f2bf(b.y); w[6] = f2bf(b.z); w[7] = f2bf(b.w);
        *(us8_t*)(dst + i) = w;
    } else if (bid < 7168) {
        // weight transpose+convert: fp32 [k][n] -> bf16 [n][k]
        const int r2 = bid - 6144;
        const int z = r2 >> 8, rem = r2 & 255;
        const float* src = (z == 0) ? w0 : (z == 1) ? w1 : (z == 2) ? w2 : w3;
        u16* dst = Wt + (size_t)z * 1048576;
        const int bk = (rem & 15) * 64, bn = (rem >> 4) * 64;
        const int r = tid >> 2, c4 = tid & 3;
        for (int i = 0; i < 4; i++) {
            float4 vv = *(const float4*)(src + (size_t)(bk + r) * 1024 + bn + c4 * 16 + i * 4);
            t[r][c4 * 16 + i * 4 + 0] = f2bf(vv.x);
            t[r][c4 * 16 + i * 4 + 1] = f2bf(vv.y);
            t[r][c4 * 16 + i * 4 + 2] = f2bf(vv.z);
            t[r][c4 * 16 + i * 4 + 3] = f2bf(vv.w);
        }
        __syncthreads();
        for (int i = 0; i < 2; i++) {
            us8_t w;
            for (int j = 0; j < 8; j++) w[j] = t[c4 * 16 + i * 8 + j][r];
            *(us8_t*)(dst + (size_t)(bn + r) * 1024 + bk + c4 * 16 + i * 8) = w;
        }
    } else {
        // mask pack: 1 bit per key
        const int w = (bid - 7168) * 256 + tid;
        const int* src = mask + (size_t)w * 32;
        unsigned bits = 0u;
        for (int i = 0; i < 32; i += 4) {
            int4 vv = *(const int4*)(src + i);
            bits |= (unsigned)(vv.x != 0) << (i + 0);
            bits |= (unsigned)(vv.y != 0) << (i + 1);
            bits |= (unsigned)(vv.z != 0) << (i + 2);
            bits |= (unsigned)(vv.w != 0) << (i + 3);
        }
        mp[w] = bits;
    }
}

// ---------------- fused QKV projection GEMM (m97-style, DMA staging) ----------------
// z=0: Q -> head-major K-swizzled; z=1: K same; z=2: V -> tiled sigma-permuted+swizzled Vtt.
// Q/K swizzle: within a 64-u16 row s, 16B chunk j stored at j ^ (s&7).
// Vtt: tile (b,h,kt): offset d*128 + (chunk^(d&7))*8 + poslow, where for key sl:
//   pos = sigma^-1(sl) = 32*(sl>>5) + 8*((sl>>2)&3) + 4*((sl>>4)&1) + (sl&3)
// so that the PV A-fragment is exactly the lane's own registers (no P transpose).
__global__ __launch_bounds__(256) void qkv_gemm_kernel(
    const u16* __restrict__ Qc, const u16* __restrict__ Kc, const u16* __restrict__ Vc,
    const u16* __restrict__ Wt,
    const float* __restrict__ bq, const float* __restrict__ bk, const float* __restrict__ bv,
    u16* __restrict__ Qh, u16* __restrict__ Kh, u16* __restrict__ Vtt)
{
    __shared__ __align__(16) u16 As[4096];
    __shared__ __align__(16) u16 Bs[4096];
    const int z = blockIdx.z;
    const u16* A = (z == 0) ? Qc : (z == 1) ? Kc : Vc;
    const u16* W = Wt + (size_t)z * 1048576;
    const float* bias = (z == 0) ? bq : (z == 1) ? bk : bv;

    const int m0 = blockIdx.x * 128, n0 = blockIdx.y * 128;
    const int tid = threadIdx.x, lane = tid & 63, wave = tid >> 6;
    const int l15 = lane & 15, quad = lane >> 4;
    const int wm = (wave & 1) * 64, wn = (wave >> 1) * 64;
    const int srow = lane >> 2, scol = (lane & 3) * 8;

    const f32x4_t z4 = {0.f, 0.f, 0.f, 0.f};
    f32x4_t acc[4][4];
    for (int i = 0; i < 4; i++) for (int j = 0; j < 4; j++) acc[i][j] = z4;

    for (int k0 = 0; k0 < 1024; k0 += 32) {
        #pragma unroll
        for (int i = 0; i < 2; i++) {
            dma16(A + (size_t)(m0 + wave * 32 + i * 16 + srow) * 1024 + k0 + scol,
                  &As[wave * 1024 + i * 512 + lane * 8]);
            dma16(W + (size_t)(n0 + wave * 32 + i * 16 + srow) * 1024 + k0 + scol,
                  &Bs[wave * 1024 + i * 512 + lane * 8]);
        }
        __syncthreads();
        bf16x8_t af[4], bfr[4];
        #pragma unroll
        for (int i = 0; i < 4; i++) af[i] = ld_bf8(&As[(wm + i * 16 + l15) * 32 + quad * 8]);
        #pragma unroll
        for (int j = 0; j < 4; j++) bfr[j] = ld_bf8(&Bs[(wn + j * 16 + l15) * 32 + quad * 8]);
        #pragma unroll
        for (int i = 0; i < 4; i++)
            #pragma unroll
            for (int j = 0; j < 4; j++)
                acc[i][j] = mfma16(af[i], bfr[j], acc[i][j]);
        __syncthreads();
    }

    #pragma unroll
    for (int i = 0; i < 4; i++) {
        const int m = m0 + wm + i * 16 + quad * 4;
        #pragma unroll
        for (int j = 0; j < 4; j++) {
            const int gn = n0 + wn + j * 16 + l15;
            const float bb = bias[gn];
            const int h = gn >> 6, dh = gn & 63;
            if (z < 2) {
                u16* Y = z ? Kh : Qh;
                const int jc = dh >> 3, e = dh & 7;
                #pragma unroll
                for (int r = 0; r < 4; r++) {
                    const int mm = m + r;
                    const int b = mm >> 11, s = mm & 2047;
                    Y[((size_t)(b * 16 + h) * 2048 + s) * 64 + ((jc ^ (s & 7)) * 8) + e] =
                        f2bf(acc[i][j][r] + bb);
                }
            } else {
                const int b = m >> 11, sh = m & 2047, kt2 = sh >> 7, sl = sh & 127;
                const int poslow = ((sl >> 4) & 1) * 4;
                const int chunk = (sl >> 5) * 4 + ((sl >> 2) & 3);
                us4_t w4;
                #pragma unroll
                for (int r = 0; r < 4; r++) w4[r] = f2bf(acc[i][j][r] + bb);
                size_t off = (((size_t)(b * 16 + h) * 16 + kt2) * 8192)
                           + (size_t)dh * 128 + ((chunk ^ (dh & 7)) * 8) + poslow;
                *(us4_t*)&Vtt[off] = w4;
            }
        }
    }
}

// ---------------- output projection GEMM: 64x128 tile (512 blocks, 2/CU) ----------------
__global__ __launch_bounds__(256) void out_gemm_kernel(
    const u16* __restrict__ X, const u16* __restrict__ Wt,
    const float* __restrict__ bias, float* __restrict__ Y)
{
    __shared__ __align__(16) u16 As[2048];
    __shared__ __align__(16) u16 Bs[4096];
    const int m0 = blockIdx.x * 64, n0 = blockIdx.y * 128;
    const int tid = threadIdx.x, lane = tid & 63, wave = tid >> 6;
    const int l15 = lane & 15, quad = lane >> 4;
    const int wm = (wave & 1) * 32, wn = (wave >> 1) * 64;
    const int srow = lane >> 2, scol = (lane & 3) * 8;

    const f32x4_t z4 = {0.f, 0.f, 0.f, 0.f};
    f32x4_t acc[2][4];
    for (int i = 0; i < 2; i++) for (int j = 0; j < 4; j++) acc[i][j] = z4;

    for (int k0 = 0; k0 < 1024; k0 += 32) {
        dma16(X + (size_t)(m0 + wave * 16 + srow) * 1024 + k0 + scol,
              &As[wave * 512 + lane * 8]);
        #pragma unroll
        for (int i = 0; i < 2; i++)
            dma16(Wt + (size_t)(n0 + wave * 32 + i * 16 + srow) * 1024 + k0 + scol,
                  &Bs[wave * 1024 + i * 512 + lane * 8]);
        __syncthreads();
        bf16x8_t af[2], bfr[4];
        #pragma unroll
        for (int i = 0; i < 2; i++) af[i] = ld_bf8(&As[(wm + i * 16 + l15) * 32 + quad * 8]);
        #pragma unroll
        for (int j = 0; j < 4; j++) bfr[j] = ld_bf8(&Bs[(wn + j * 16 + l15) * 32 + quad * 8]);
        #pragma unroll
        for (int i = 0; i < 2; i++)
            #pragma unroll
            for (int j = 0; j < 4; j++)
                acc[i][j] = mfma16(af[i], bfr[j], acc[i][j]);
        __syncthreads();
    }

    #pragma unroll
    for (int i = 0; i < 2; i++) {
        const int m = m0 + wm + i * 16 + quad * 4;
        #pragma unroll
        for (int j = 0; j < 4; j++) {
            const int gn = n0 + wn + j * 16 + l15;
            const float bb = bias[gn];
            #pragma unroll
            for (int r = 0; r < 4; r++)
                Y[(size_t)(m + r) * 1024 + gn] = acc[i][j][r] + bb;
        }
    }
}

// ---------------- flash attention v5: transposed QK^T, register P, dbuf K/V ----------------
// grid (h=16, qb=16, b=2): h fastest -> XCD = h%8 -> 4 heads' K+V (2MB) per XCD L2.
// 4 waves x 32 q-rows. S^T = K·Q^T puts scores at col=qrow(l15), row=key(quad*4+r);
// V's key-dim is sigma-permuted globally so the PV A-frag = lane's own exp'd registers.
// K+V double-buffered (64KB), ONE barrier/iter, DMA(t+1) issued at iter top.
__global__ __launch_bounds__(256) void attn_kernel(
    const u16* __restrict__ Qh, const u16* __restrict__ Kh,
    const u16* __restrict__ Vtt, const unsigned* __restrict__ mp,
    u16* __restrict__ C)
{
    __shared__ __align__(16) u16 Ks[2][8192];
    __shared__ __align__(16) u16 Vs[2][8192];
    const int h = blockIdx.x, qb = blockIdx.y, b = blockIdx.z;
    const int tid = threadIdx.x, lane = tid & 63, wave = tid >> 6;
    const int l15 = lane & 15, quad = lane >> 4;
    const int q0 = qb * 128 + wave * 32;
    const int grow = b * 2048 + q0;
    const size_t headoff = (size_t)(b * 16 + h) * 131072;
    const u16* Qg = Qh + headoff;
    const u16* Kg = Kh + headoff;
    const u16* Vg = Vtt + headoff;

    bf16x8_t aq[2][2];
    #pragma unroll
    for (int h2 = 0; h2 < 2; h2++)
        #pragma unroll
        for (int ks = 0; ks < 2; ks++)
            aq[h2][ks] = ld_bf8(Qg + (size_t)(q0 + h2 * 16 + l15) * 64
                                   + (((ks * 4 + quad) ^ (l15 & 7)) * 8));

    const f32x4_t z4 = {0.f, 0.f, 0.f, 0.f};
    f32x4_t o[2][4];
    #pragma unroll
    for (int h2 = 0; h2 < 2; h2++)
        #pragma unroll
        for (int i = 0; i < 4; i++) o[h2][i] = z4;
    float psum[2] = {0.f, 0.f};

    const int swA = (quad ^ (l15 & 7)) * 8;
    const int swB = ((4 + quad) ^ (l15 & 7)) * 8;

    const unsigned* mrow0 = mp + (size_t)(b * 2048 + q0 + l15) * 64;
    const unsigned* mrow1 = mp + (size_t)(b * 2048 + q0 + 16 + l15) * 64;

    // stage tile kt into buffer bs: each wave DMAs its quarter of K and V (8KB)
    auto stage = [&](int kt, int bs) {
        const u16* kg = Kg + kt * 8192 + wave * 2048;
        const u16* vg = Vg + kt * 8192 + wave * 2048;
        u16* kl = &Ks[bs][wave * 2048];
        u16* vl = &Vs[bs][wave * 2048];
        #pragma unroll
        for (int i = 0; i < 4; i++) {
            dma16(kg + i * 512 + lane * 8, kl + i * 512 + lane * 8);
            dma16(vg + i * 512 + lane * 8, vl + i * 512 + lane * 8);
        }
    };

    stage(0, 0);

    for (int kt = 0; kt < 16; ++kt) {
        const int bs = kt & 1;
        __syncthreads();              // drains DMA(kt); buf bs^1 is free (consumed in kt-1)
        if (kt < 15) stage(kt + 1, bs ^ 1);

        int4 mq0 = *(const int4*)(mrow0 + kt * 4);
        int4 mq1 = *(const int4*)(mrow1 + kt * 4);

        // --- S^T = K·Q^T : rows=keys, cols=qrows ---
        f32x4_t sc[2][8];
        #pragma unroll
        for (int st = 0; st < 8; st++) {
            const u16* kp = &Ks[bs][(st * 16 + l15) * 64];
            bf16x8_t k0 = ld_bf8(kp + swA);
            bf16x8_t k1 = ld_bf8(kp + swB);
            sc[0][st] = mfma16(k1, aq[0][1], mfma16(k0, aq[0][0], z4));
            sc[1][st] = mfma16(k1, aq[1][1], mfma16(k0, aq[1][0], z4));
        }

        // --- fixed-max softmax in registers; pack P directly into A-fragments ---
        us8_t ap[2][4];
        #pragma unroll
        for (int h2 = 0; h2 < 2; h2++) {
            const unsigned* mw = h2 ? (const unsigned*)&mq1 : (const unsigned*)&mq0;
            float ps = 0.f;
            #pragma unroll
            for (int st = 0; st < 8; st++) {
                const unsigned w = mw[st >> 1];
                const int shbase = ((st & 1) << 4) + quad * 4;
                #pragma unroll
                for (int r = 0; r < 4; r++) {
                    const bool msk = (w >> (shbase + r)) & 1u;
                    const float t = fmaf(sc[h2][st][r], 0.125f, msk ? -1e5f : -12.0f);
                    const float p = __expf(t);
                    ps += p;
                    ap[h2][st >> 1][((st & 1) << 2) + r] = f2bf(p);
                }
            }
            psum[h2] += ps;
        }

        // --- PV: A-frag from registers, B-frag from sigma-permuted V tile ---
        #pragma unroll
        for (int c = 0; c < 4; c++) {
            bf16x8_t a0 = __builtin_bit_cast(bf16x8_t, ap[0][c]);
            bf16x8_t a1 = __builtin_bit_cast(bf16x8_t, ap[1][c]);
            #pragma unroll
            for (int nt = 0; nt < 4; nt++) {
                bf16x8_t bv = ld_bf8(&Vs[bs][(nt * 16 + l15) * 128
                                             + (((c * 4 + quad) ^ (l15 & 7)) * 8)]);
                o[0][nt] = mfma16(a0, bv, o[0][nt]);
                o[1][nt] = mfma16(a1, bv, o[1][nt]);
            }
        }
    }

    // psum lives at (l15 = qrow); reduce over the 4 quad-copies, then redistribute
    #pragma unroll
    for (int h2 = 0; h2 < 2; h2++) {
        psum[h2] += __shfl_xor(psum[h2], 16);
        psum[h2] += __shfl_xor(psum[h2], 32);
    }
    #pragma unroll
    for (int h2 = 0; h2 < 2; h2++)
        #pragma unroll
        for (int r = 0; r < 4; r++) {
            const float invl = 1.0f / __shfl(psum[h2], quad * 4 + r);
            const int row = grow + h2 * 16 + quad * 4 + r;
            #pragma unroll
            for (int nt = 0; nt < 4; nt++)
                C[(size_t)row * 1024 + h * 64 + nt * 16 + l15] = f2bf(o[h2][nt][r] * invl);
        }
}

extern "C" void kernel_launch(void* const* d_in, const int* in_sizes, int n_in,
                              void* d_out, int out_size, void* d_ws, size_t ws_size,
                              hipStream_t stream) {
    const float* q    = (const float*)d_in[0];
    const float* k    = (const float*)d_in[1];
    const float* v    = (const float*)d_in[2];
    const int*   mask = (const int*)d_in[3];
    const float* wq   = (const float*)d_in[4];
    const float* bq   = (const float*)d_in[5];
    const float* wk   = (const float*)d_in[6];
    const float* bk   = (const float*)d_in[7];
    const float* wv   = (const float*)d_in[8];
    const float* bv   = (const float*)d_in[9];
    const float* wo   = (const float*)d_in[10];
    const float* bo   = (const float*)d_in[11];
    float* out = (float*)d_out;

    char* ws = (char*)d_ws;
    const size_t MB = 1ull << 20;
    u16* Wt      = (u16*)(ws);              // 8 MB: 4 weights bf16 [n][k]
    u16* Qc      = (u16*)(ws + 8 * MB);     // 8 MB bf16 input q
    u16* Kc      = (u16*)(ws + 16 * MB);    // 8 MB bf16 input k
    u16* Vc      = (u16*)(ws + 24 * MB);    // 8 MB bf16 input v
    u16* Qhh     = (u16*)(ws + 32 * MB);    // 8 MB head-major swizzled
    u16* Khh     = (u16*)(ws + 40 * MB);    // 8 MB head-major swizzled
    u16* Vtt     = (u16*)(ws + 48 * MB);    // 8 MB tiled sigma-permuted swizzled
    u16* CT      = (u16*)(ws + 8 * MB);     // reuse Qc (dead after qkv_gemm)
    unsigned* mp = (unsigned*)(ws + 56 * MB); // 1 MB

    prep_kernel<<<dim3(8192), 256, 0, stream>>>(
        q, k, v, mask, wq, wk, wv, wo, Qc, Kc, Vc, Wt, mp);

    qkv_gemm_kernel<<<dim3(32, 8, 3), 256, 0, stream>>>(
        Qc, Kc, Vc, Wt, bq, bk, bv, Qhh, Khh, Vtt);

    attn_kernel<<<dim3(16, 16, 2), 256, 0, stream>>>(Qhh, Khh, Vtt, mp, CT);

    out_gemm_kernel<<<dim3(64, 8), 256, 0, stream>>>(CT, Wt + 3ull * 1048576, bo, out);
}